// Round 1
// baseline (1167.476 us; speedup 1.0000x reference)
//
#include <hip/hip_runtime.h>
#include <cstdint>
#include <cstddef>

#define NN 100000
#define NE 1600000

// ---------------- graph preprocessing ----------------

static __global__ void k_init_deg(int* __restrict__ deg) {
    int i = blockIdx.x * 256 + threadIdx.x;
    if (i < NN) deg[i] = 1;  // self loop
}

static __global__ void k_count(const int* __restrict__ dst, int* __restrict__ deg) {
    int e = blockIdx.x * 256 + threadIdx.x;
    if (e < NE) atomicAdd(&deg[dst[e]], 1);
}

static __global__ void k_dinv(const int* __restrict__ deg, float* __restrict__ dinv) {
    int i = blockIdx.x * 256 + threadIdx.x;
    if (i < NN) dinv[i] = rsqrtf((float)deg[i]);  // deg >= 1 always
}

// exclusive scan of (deg[i]-1) -> row_ptr, chunk=1024/block
static __global__ void k_scan1(const int* __restrict__ deg, int* __restrict__ row_ptr,
                               int* __restrict__ bsums) {
    __shared__ int sd[256];
    int t = threadIdx.x;
    int base = blockIdx.x * 1024;
    int v[4];
    int s = 0;
#pragma unroll
    for (int j = 0; j < 4; j++) {
        int i = base + t * 4 + j;
        int c = (i < NN) ? (deg[i] - 1) : 0;
        v[j] = s;
        s += c;
    }
    sd[t] = s;
    __syncthreads();
    for (int off = 1; off < 256; off <<= 1) {
        int x = (t >= off) ? sd[t - off] : 0;
        __syncthreads();
        sd[t] += x;
        __syncthreads();
    }
    int excl = (t > 0) ? sd[t - 1] : 0;
#pragma unroll
    for (int j = 0; j < 4; j++) {
        int i = base + t * 4 + j;
        if (i < NN) row_ptr[i] = excl + v[j];
    }
    if (t == 255) bsums[blockIdx.x] = sd[255];
}

static __global__ void k_scan2(int* __restrict__ bsums, int nb) {
    if (blockIdx.x == 0 && threadIdx.x == 0) {
        int s = 0;
        for (int i = 0; i < nb; i++) {
            int c = bsums[i];
            bsums[i] = s;
            s += c;
        }
    }
}

static __global__ void k_scan3(int* __restrict__ row_ptr, int* __restrict__ cursor,
                               const int* __restrict__ bsums) {
    int i = blockIdx.x * 256 + threadIdx.x;
    if (i < NN) {
        int v = row_ptr[i] + bsums[i >> 10];
        row_ptr[i] = v;
        cursor[i] = v;
    } else if (i == NN) {
        row_ptr[NN] = NE;
    }
}

static __global__ void k_fill(const int* __restrict__ src, const int* __restrict__ dst,
                              int* __restrict__ cursor, int* __restrict__ csr_src) {
    int e = blockIdx.x * 256 + threadIdx.x;
    if (e < NE) {
        int d = dst[e];
        int pos = atomicAdd(&cursor[d], 1);
        csr_src[pos] = src[e];
    }
}

// ---------------- dense GEMM ----------------
// C[N, DOUT] = A[N, DIN] @ W   (W either [DIN, DOUT] or, if TRANSB, [DOUT, DIN] accessed as W^T)
// RESID: C = relu(A + A@W^T)  (requires DIN==DOUT)
template <int DIN, int DOUT, bool TRANSB, bool RESID>
__global__ __launch_bounds__(256, 2) void k_gemm(const float* __restrict__ A,
                                                 const float* __restrict__ W,
                                                 float* __restrict__ C) {
    static_assert(!RESID || DIN == DOUT, "residual needs square");
    constexpr int COLS = DOUT / 32;  // 4 for 128, 2 for 64
    constexpr int LDW = DIN + 4;     // padded leading dim for transposed layout
    __shared__ float Ws[TRANSB ? (DOUT * LDW) : (DIN * DOUT)];
    const int t = threadIdx.x;

    if constexpr (!TRANSB) {
        const float4* Wv = (const float4*)W;
        float4* Sv = (float4*)Ws;
        for (int i = t; i < DIN * DOUT / 4; i += 256) Sv[i] = Wv[i];
    } else {
        constexpr int K4 = DIN / 4;
        for (int i = t; i < DOUT * K4; i += 256) {
            int j = i / K4, k4 = i - j * K4;
            float4 v = ((const float4*)W)[i];
            *(float4*)&Ws[j * LDW + 4 * k4] = v;
        }
    }
    __syncthreads();

    const int cg = t & 31;
    const int rg = t >> 5;
    const int n0 = blockIdx.x * 64 + rg * 8;

    float acc[8][COLS];
#pragma unroll
    for (int r = 0; r < 8; r++)
#pragma unroll
        for (int c = 0; c < COLS; c++) acc[r][c] = 0.f;

    int rowi[8];
#pragma unroll
    for (int r = 0; r < 8; r++) rowi[r] = min(n0 + r, NN - 1);  // clamp tail; store guarded

    for (int k = 0; k < DIN; k += 4) {
        float w[4][COLS];
        if constexpr (!TRANSB) {
#pragma unroll
            for (int kk = 0; kk < 4; kk++) {
                if constexpr (COLS == 4) {
                    float4 wv = *(const float4*)&Ws[(k + kk) * DOUT + 4 * cg];
                    w[kk][0] = wv.x; w[kk][1] = wv.y; w[kk][2] = wv.z; w[kk][3] = wv.w;
                } else {
                    float2 wv = *(const float2*)&Ws[(k + kk) * DOUT + 2 * cg];
                    w[kk][0] = wv.x; w[kk][1] = wv.y;
                }
            }
        } else {
#pragma unroll
            for (int c = 0; c < COLS; c++) {
                float4 wv = *(const float4*)&Ws[(cg + 32 * c) * LDW + k];
                w[0][c] = wv.x; w[1][c] = wv.y; w[2][c] = wv.z; w[3][c] = wv.w;
            }
        }
#pragma unroll
        for (int r = 0; r < 8; r++) {
            float4 a = *(const float4*)&A[(size_t)rowi[r] * DIN + k];
#pragma unroll
            for (int c = 0; c < COLS; c++)
                acc[r][c] = fmaf(a.x, w[0][c],
                            fmaf(a.y, w[1][c],
                            fmaf(a.z, w[2][c],
                            fmaf(a.w, w[3][c], acc[r][c]))));
        }
    }

#pragma unroll
    for (int r = 0; r < 8; r++) {
        int row = n0 + r;
        if (row < NN) {
#pragma unroll
            for (int c = 0; c < COLS; c++) {
                int col = TRANSB ? (cg + 32 * c) : (COLS * cg + c);
                float v = acc[r][c];
                if constexpr (RESID) {
                    v += A[(size_t)row * DIN + col];
                    v = fmaxf(v, 0.f);
                }
                C[(size_t)row * DOUT + col] = v;
            }
        }
    }
}

// ---------------- GCN aggregation ----------------
// out[i] = relu( b + dinv[i] * ( dinv[i]*h[i] + sum_e dinv[src_e]*h[src_e] ) )
// one wave per node; lane handles D/64 contiguous channels.
template <int D>
__global__ __launch_bounds__(256) void k_agg(const float* __restrict__ h,
                                             const float* __restrict__ dinv,
                                             const int* __restrict__ row_ptr,
                                             const int* __restrict__ csr_src,
                                             const float* __restrict__ bias,
                                             float* __restrict__ out) {
    constexpr int CPL = D / 64;
    int node = blockIdx.x * 4 + (threadIdx.x >> 6);
    int lane = threadIdx.x & 63;
    if (node >= NN) return;

    float di = dinv[node];
    const float* hp = h + (size_t)node * D;
    float acc[CPL];
#pragma unroll
    for (int c = 0; c < CPL; c++) acc[c] = di * hp[lane * CPL + c];

    int e = row_ptr[node];
    int end = row_ptr[node + 1];
    for (; e < end; e++) {
        int s = csr_src[e];
        float w = dinv[s];
        const float* hs = h + (size_t)s * D;
#pragma unroll
        for (int c = 0; c < CPL; c++) acc[c] = fmaf(w, hs[lane * CPL + c], acc[c]);
    }

#pragma unroll
    for (int c = 0; c < CPL; c++) {
        int ch = lane * CPL + c;
        out[(size_t)node * D + ch] = fmaxf(fmaf(di, acc[c], bias[ch]), 0.f);
    }
}

// ---------------- launch ----------------

extern "C" void kernel_launch(void* const* d_in, const int* in_sizes, int n_in,
                              void* d_out, int out_size, void* d_ws, size_t ws_size,
                              hipStream_t stream) {
    const float* x   = (const float*)d_in[0];
    const int*   ei  = (const int*)d_in[1];
    const float* g1w = (const float*)d_in[2];
    const float* g1b = (const float*)d_in[3];
    const float* f2w = (const float*)d_in[4];
    const float* g3w = (const float*)d_in[5];
    const float* g3b = (const float*)d_in[6];
    const float* f4w = (const float*)d_in[7];
    const float* g5w = (const float*)d_in[8];
    const float* g5b = (const float*)d_in[9];
    const float* f6w = (const float*)d_in[10];
    float* out = (float*)d_out;

    const int* src = ei;       // edge_index[0]
    const int* dst = ei + NE;  // edge_index[1]

    char* p = (char*)d_ws;
    auto alloc = [&](size_t bytes) -> void* {
        void* r = (void*)p;
        p += (bytes + 255) & ~(size_t)255;
        return r;
    };
    int*   deg     = (int*)alloc(NN * 4);
    float* dinv    = (float*)alloc(NN * 4);
    int*   row_ptr = (int*)alloc((NN + 1) * 4);
    int*   cursor  = (int*)alloc(NN * 4);
    int*   bsums   = (int*)alloc(512);
    int*   csr     = (int*)alloc(NE * 4);
    float* bufA    = (float*)alloc((size_t)NN * 128 * 4);
    float* bufB    = (float*)alloc((size_t)NN * 128 * 4);

    const int gN  = (NN + 255) / 256;
    const int gE  = (NE + 255) / 256;
    const int gS  = (NN + 1023) / 1024;     // 98
    const int gN1 = (NN + 1 + 255) / 256;
    const int gG  = (NN + 63) / 64;         // 1563
    const int gA  = NN / 4;                 // 25000

    // graph preprocessing
    k_init_deg<<<gN, 256, 0, stream>>>(deg);
    k_count<<<gE, 256, 0, stream>>>(dst, deg);
    k_dinv<<<gN, 256, 0, stream>>>(deg, dinv);
    k_scan1<<<gS, 256, 0, stream>>>(deg, row_ptr, bsums);
    k_scan2<<<1, 64, 0, stream>>>(bsums, gS);
    k_scan3<<<gN1, 256, 0, stream>>>(row_ptr, cursor, bsums);
    k_fill<<<gE, 256, 0, stream>>>(src, dst, cursor, csr);

    // layer 1: z1 = relu(agg(x @ W1) + b1); z1' = relu(z1 + z1 @ fc2^T)
    k_gemm<128, 128, false, false><<<gG, 256, 0, stream>>>(x, g1w, bufA);
    k_agg<128><<<gA, 256, 0, stream>>>(bufA, dinv, row_ptr, csr, g1b, bufB);
    k_gemm<128, 128, true, true><<<gG, 256, 0, stream>>>(bufB, f2w, bufA);

    // layer 2: z2 = relu(agg(z1' @ W3) + b3); z2' = relu(z2 + z2 @ fc4^T)
    k_gemm<128, 64, false, false><<<gG, 256, 0, stream>>>(bufA, g3w, bufB);
    k_agg<64><<<gA, 256, 0, stream>>>(bufB, dinv, row_ptr, csr, g3b, bufA);
    k_gemm<64, 64, true, true><<<gG, 256, 0, stream>>>(bufA, f4w, bufB);

    // layer 3: z3 = relu(agg(z2' @ W5) + b5); out = relu(z3 + z3 @ fc6^T)
    k_gemm<64, 128, false, false><<<gG, 256, 0, stream>>>(bufB, g5w, bufA);
    k_agg<128><<<gA, 256, 0, stream>>>(bufA, dinv, row_ptr, csr, g5b, bufB);
    k_gemm<128, 128, true, true><<<gG, 256, 0, stream>>>(bufB, f6w, out);
}